// Round 5
// baseline (127.149 us; speedup 1.0000x reference)
//
#include <hip/hip_runtime.h>

#define L 4096
#define LANES 64
#define NCH (L / LANES)   // 64 chunks of 64 per row, one wave per row
#define DPAD 64
typedef unsigned long long u64;
typedef unsigned u32;
#define SENT32 0xFFFFFFFFu  // kept marker; real keys <= 0x7F800001

template<int CTRL, int RM>
static __device__ __forceinline__ u32 dpp32(u32 v) {
    u32 s = (u32)__builtin_amdgcn_update_dpp(0, (int)v, CTRL, RM, 0xf, false);
    return v > s ? v : s;   // out-of-row lanes contribute 0 (identity)
}
// Inclusive 64-lane prefix-max (R4-verified scan sequence, now u32).
static __device__ __forceinline__ u32 scanmax32(u32 v) {
    v = dpp32<0x111, 0xf>(v);  // row_shr:1
    v = dpp32<0x112, 0xf>(v);  // row_shr:2
    v = dpp32<0x114, 0xf>(v);  // row_shr:4
    v = dpp32<0x118, 0xf>(v);  // row_shr:8
    v = dpp32<0x142, 0xa>(v);  // row_bcast:15
    v = dpp32<0x143, 0xc>(v);  // row_bcast:31
    return v;
}

// enc[i]: active extremum -> bits(|x|)+1 (monotone in |x|, never 0/SENT32);
// 0 = none/suppressed; SENT32 = kept. Ties (equal |x| within a window) are
// resolved exactly (smaller index first, as JAX stable argsort) via
// per-candidate equality ballots. Single wave per row: no races, full
// Gauss-Seidel freshness per sweep; each zigzag pass commits at least the
// global max of the remaining actives -> guaranteed termination.
__global__ __launch_bounds__(LANES)
void extrema1d_kernel(const float* __restrict__ x,
                      const int* __restrict__ dptr,
                      float* __restrict__ out) {
    __shared__ float s_x[L];
    __shared__ u32 s_enc_raw[L + 2 * DPAD];
    __shared__ u64 s_enc64_raw[L + 2 * DPAD];  // generic-d fallback only
    u32* enc = s_enc_raw + DPAD;

    const int row = blockIdx.x;
    const int lane = threadIdx.x;
    const int d = *dptr;
    const float* __restrict__ xrow = x + (size_t)row * L;

    // ---- stage row (lane-dense float4 = coalesced 1KB/wave-instr) ----
    #pragma unroll
    for (int t = 0; t < 16; ++t) {
        int f = t * 64 + lane;
        ((float4*)s_x)[f] = ((const float4*)xrow)[f];
    }
    s_enc_raw[lane] = 0;
    s_enc_raw[L + DPAD + lane] = 0;
    __syncthreads();

    // ---- extrema -> keys, 4 positions/lane/iter ----
    // Reference pads: dxr[L-1]=false, dxl[0]=true, neg = !(x>0).
    #pragma unroll 2
    for (int t = 0; t < 16; ++t) {
        int f = t * 64 + lane;
        int base = 4 * f;
        float4 xv = ((const float4*)s_x)[f];
        float xl = (base == 0) ? 0.0f : s_x[base - 1];
        float xr = (base + 4 >= L) ? 0.0f : s_x[base + 4];
        float nb[6] = {xl, xv.x, xv.y, xv.z, xv.w, xr};
        uint4 ev;
        u32* evp = (u32*)&ev;
        #pragma unroll
        for (int j = 0; j < 4; ++j) {
            int p = base + j;
            float xi = nb[j + 1];
            bool dxr = (p < L - 1) && ((nb[j + 2] - xi) > 0.0f);
            bool dxl = (p == 0) || ((xi - nb[j]) <= 0.0f);
            bool neg = !(xi > 0.0f);
            bool ext = (dxr && dxl && neg) || (!dxr && !dxl && !neg);
            evp[j] = ext ? (__float_as_uint(fabsf(xi)) + 1u) : 0u;
        }
        ((uint4*)&enc[base])[0] = ev;
    }
    __syncthreads();

    u64 alive = ~0ULL;  // bit k <-> position 64k+lane; first visit cleans non-extrema

    if (d == 32) {
        int dir = 0;
        for (int pass = 0; pass < 1024; ++pass) {
            if (!__ballot(alive != 0ULL)) break;
            for (int kk = 0; kk < NCH; ++kk) {
                int k = dir ? (NCH - 1 - kk) : kk;
                if (!__ballot((alive >> k) & 1ULL)) continue;
                const int q0 = k << 6;
                const int p = q0 + lane;
                u32 ePr = 0, eN = 0, S_P = 0, P_n = 0;
                bool first = true;
                for (int rep = 0; rep < 3; ++rep) {
                    bool act = (alive >> k) & 1ULL;
                    u32 eC = enc[p];              // fresh own chunk
                    u32 eCr = enc[q0 + 63 - lane];
                    if (act && eC == 0u) { alive &= ~(1ULL << k); act = false; }
                    if (!__ballot(act)) break;
                    if (first) {                  // neighbor chunks: cached across
                        ePr = enc[q0 - 64 + 63 - lane];  // reps (stale only shrinks
                        eN  = enc[q0 + 64 + lane];       // -> defer-only, safe)
                        S_P = scanmax32(ePr);
                        P_n = scanmax32(eN);
                        first = false;
                    }
                    u32 P_c = scanmax32(eC);
                    u32 S_C = scanmax32(eCr);
                    // Gil-Werman window [p-32,p+32] (R4-verified lane math)
                    u32 sendS = (lane < 32) ? S_P : S_C;
                    u32 sendP = (lane < 32) ? P_n : P_c;
                    int idxP = lane ^ 32;
                    u32 a1 = (u32)__shfl((int)sendS, 63 - idxP);
                    u32 a2 = (u32)__shfl((int)sendP, idxP);
                    u32 wm = a1 > a2 ? a1 : a2;
                    bool cand = act && (wm == eC);   // no strictly-larger in window
                    u64 Mc = __ballot(cand);
                    u64 M = 0;
                    while (Mc) {                     // exact tie-break, ~1 iter typ.
                        int c = __ffsll((long long)Mc) - 1;
                        Mc &= Mc - 1;
                        u32 vc = (u32)__shfl((int)eC, c);
                        u64 eqC = __ballot(eC == vc);    // natural order
                        u64 eqP = __ballot(ePr == vc);   // bit l <-> prev[63-l]
                        int lo = c - 32; if (lo < 0) lo = 0;
                        u64 belowC = (c == 0) ? 0ULL
                                   : (((1ULL << c) - 1ULL) & ~((1ULL << lo) - 1ULL));
                        u64 blockP = (c <= 31) ? (eqP & ((1ULL << (32 - c)) - 1ULL))
                                               : 0ULL;
                        // win iff no equal key at smaller index within window
                        if (((eqC & belowC) | blockP) == 0ULL) M |= (1ULL << c);
                    }
                    if (M == 0ULL) break;            // all deferred -> next chunk
                    bool winlane = (M >> lane) & 1ULL;
                    if (winlane) {
                        enc[p] = SENT32;
                        alive &= ~(1ULL << k);
                    }
                    // ---- ballot-mask suppression: 3 predicated writes/lane ----
                    {
                        int lo = lane - 32; if (lo < 0) lo = 0;
                        int hi = lane + 32; if (hi > 63) hi = 63;
                        u64 mwin = ((hi == 63) ? ~0ULL : ((1ULL << (hi + 1)) - 1ULL))
                                 & ~((1ULL << lo) - 1ULL);
                        bool supS = !winlane && ((M & mwin & ~(1ULL << lane)) != 0ULL);
                        bool supP = (lane >= 32) &&
                                    ((M & ((1ULL << (lane - 31)) - 1ULL)) != 0ULL);
                        bool supN = (lane < 32) &&
                                    ((M & (~0ULL << (lane + 32))) != 0ULL);
                        if (supS) { enc[p] = 0u; alive &= ~(1ULL << k); }
                        if (supP) { enc[p - 64] = 0u; if (k > 0) alive &= ~(1ULL << (k - 1)); }
                        if (supN) { enc[p + 64] = 0u; if (k < NCH - 1) alive &= ~(1ULL << (k + 1)); }
                    }
                }
            }
            dir ^= 1;
        }
    } else {
        // ---- generic-d fallback: u64 keys (index tie-break in low bits) ----
        u64* enc64 = s_enc64_raw + DPAD;
        for (int k = 0; k < NCH; ++k) {
            int p = (k << 6) + lane;
            u32 e = enc[p];
            enc64[p] = e ? ((((u64)e) << 12) | (u64)(4095 - p)) : 0ULL;
        }
        s_enc64_raw[lane] = 0;
        s_enc64_raw[L + DPAD + lane] = 0;
        __syncthreads();
        int dir = 0;
        for (int pass = 0; pass < 2048; ++pass) {
            if (!__ballot(alive != 0ULL)) break;
            for (int kk = 0; kk < NCH; ++kk) {
                int k = dir ? (NCH - 1 - kk) : kk;
                bool act = (alive >> k) & 1ULL;
                if (!__ballot(act)) continue;
                int p = (k << 6) + lane;
                u64 me = 0;
                if (act) {
                    me = enc64[p];
                    if (me == 0ULL) { alive &= ~(1ULL << k); act = false; }
                }
                if (!__ballot(act)) continue;
                u64 best = 0;
                int lo = p - d; if (lo < 0) lo = 0;
                int hi = p + d; if (hi > L - 1) hi = L - 1;
                if (act)
                    for (int j = lo; j <= hi; ++j)
                        if (j != p) best = best > enc64[j] ? best : enc64[j];
                if (act && best < me) {
                    enc64[p] = ~0ULL;
                    enc[p] = SENT32;   // mirror for emit
                    alive &= ~(1ULL << k);
                    for (int j = lo; j <= hi; ++j)
                        if (j != p) enc64[j] = 0ULL;
                }
            }
            dir ^= 1;
        }
    }
    __syncthreads();

    // ---- emit: kept -> x, else 0 (vectorized, coalesced) ----
    float* __restrict__ orow = out + (size_t)row * L;
    #pragma unroll 2
    for (int t = 0; t < 16; ++t) {
        int f = t * 64 + lane;
        int base = 4 * f;
        uint4 ev = ((const uint4*)&enc[base])[0];
        float4 xv = ((const float4*)s_x)[f];
        float4 o;
        o.x = (ev.x == SENT32) ? xv.x : 0.0f;
        o.y = (ev.y == SENT32) ? xv.y : 0.0f;
        o.z = (ev.z == SENT32) ? xv.z : 0.0f;
        o.w = (ev.w == SENT32) ? xv.w : 0.0f;
        ((float4*)orow)[f] = o;
    }
}

extern "C" void kernel_launch(void* const* d_in, const int* in_sizes, int n_in,
                              void* d_out, int out_size, void* d_ws, size_t ws_size,
                              hipStream_t stream) {
    const float* x = (const float*)d_in[0];
    const int* dptr = (const int*)d_in[1];
    float* out = (float*)d_out;
    const int B = out_size / L;  // 128 rows, one wave each
    extrema1d_kernel<<<B, LANES, 0, stream>>>(x, dptr, out);
}

// Round 6
// 68.113 us; speedup vs baseline: 1.8667x; 1.8667x over previous
//
#include <hip/hip_runtime.h>

#define L 4096
#define BLOCK 512
#define LANES 64
#define NWAVE (BLOCK / LANES)     // 8 waves per row
#define NCH (L / LANES)           // 64 chunks of 64
#define CPW (NCH / NWAVE)         // 8 chunks per wave (contiguous segment)
#define DPAD 64
typedef unsigned long long u64;
typedef unsigned u32;
#define SENT32 0xFFFFFFFFu        // kept marker; real keys <= 0x7F800002

template<int CTRL, int RM>
static __device__ __forceinline__ u32 dpp32(u32 v) {
    u32 s = (u32)__builtin_amdgcn_update_dpp(0, (int)v, CTRL, RM, 0xf, false);
    return v > s ? v : s;   // bound_ctrl=false, old=0 -> identity off-row
}
// Inclusive 64-lane prefix-max (R4/R5-verified DPP sequence).
static __device__ __forceinline__ u32 scanmax32(u32 v) {
    v = dpp32<0x111, 0xf>(v);  // row_shr:1
    v = dpp32<0x112, 0xf>(v);  // row_shr:2
    v = dpp32<0x114, 0xf>(v);  // row_shr:4
    v = dpp32<0x118, 0xf>(v);  // row_shr:8
    v = dpp32<0x142, 0xa>(v);  // row_bcast:15
    v = dpp32<0x143, 0xc>(v);  // row_bcast:31
    return v;
}

// enc[i]: active -> bits(|x|)+1; 0 = none/suppressed; SENT32 = kept.
// Monotone slot history (key -> {0|SENT32}, both terminal) means an ALIVE
// item is always read at its exact key by any wave; stale reads can only
// over-estimate dead neighbors -> defer-only. Hence the 8-wave chaotic
// iteration commits exactly the sequential-greedy fixed point; ties (|x|
// equal within a window) resolved exactly via equality ballots (smaller
// index wins = JAX stable argsort). Winners suppress their full +-32 window,
// so no alive item ever neighbors a kept marker (no deadlock).
__global__ __launch_bounds__(BLOCK)
void extrema1d_kernel(const float* __restrict__ x,
                      const int* __restrict__ dptr,
                      float* __restrict__ out) {
    __shared__ float s_x[L];
    __shared__ u32 s_enc_raw[L + 2 * DPAD];
    __shared__ u64 s_enc64_raw[L + 2 * DPAD];  // generic-d fallback only
    u32* enc = s_enc_raw + DPAD;

    const int row = blockIdx.x;
    const int tid = threadIdx.x;
    const int lane = tid & (LANES - 1);
    const int wave = tid >> 6;
    const int d = *dptr;
    const float* __restrict__ xrow = x + (size_t)row * L;

    // ---- stage row (coalesced float4, 2 per thread) ----
    #pragma unroll
    for (int t = 0; t < 2; ++t) {
        int f = t * BLOCK + tid;
        ((float4*)s_x)[f] = ((const float4*)xrow)[f];
    }
    if (tid < 2 * DPAD)
        s_enc_raw[(tid < DPAD) ? tid : (DPAD + L + (tid - DPAD))] = 0u;
    __syncthreads();

    // ---- extrema -> keys (reference pads: dxr[L-1]=F, dxl[0]=T, neg=!(x>0))
    #pragma unroll
    for (int t = 0; t < 2; ++t) {
        int f = t * BLOCK + tid;
        int base = 4 * f;
        float4 xv = ((const float4*)s_x)[f];
        float xl = (base == 0) ? 0.0f : s_x[base - 1];
        float xr = (base + 4 >= L) ? 0.0f : s_x[base + 4];
        float nb[6] = {xl, xv.x, xv.y, xv.z, xv.w, xr};
        uint4 ev; u32* evp = (u32*)&ev;
        #pragma unroll
        for (int j = 0; j < 4; ++j) {
            int p = base + j;
            float xi = nb[j + 1];
            bool dxr = (p < L - 1) && ((nb[j + 2] - xi) > 0.0f);
            bool dxl = (p == 0) || ((xi - nb[j]) <= 0.0f);
            bool neg = !(xi > 0.0f);
            bool ext = (dxr && dxl && neg) || (!dxr && !dxl && !neg);
            evp[j] = ext ? (__float_as_uint(fabsf(xi)) + 1u) : 0u;
        }
        ((uint4*)&enc[base])[0] = ev;
    }
    __syncthreads();

    if (d == 32) {
        const int seg0 = wave * CPW;
        u32 alive = (1u << CPW) - 1u;   // bit kl <-> pos (seg0+kl)*64+lane
        int dir = 0;
        for (int pass = 0; pass < 512; ++pass) {
            if (!__ballot((int)(alive != 0u))) break;
            for (int kk = 0; kk < CPW; ++kk) {
                int kl = dir ? (CPW - 1 - kk) : kk;
                if (!__ballot((int)((alive >> kl) & 1u))) continue;
                const int q0 = (seg0 + kl) << 6;
                const int p = q0 + lane;
                u32 ePr = 0, S_P = 0, P_n = 0;
                bool first = true;
                for (int rep = 0; rep < 3; ++rep) {
                    bool act = (alive >> kl) & 1u;
                    u32 eC  = ((volatile u32*)enc)[p];             // fresh own
                    u32 eCr = ((volatile u32*)enc)[q0 + 63 - lane];
                    if (act && eC == 0u) { alive &= ~(1u << kl); act = false; }
                    if (!__ballot((int)act)) break;
                    if (first) {   // neighbor chunks cached per visit (defer-only)
                        ePr = ((volatile u32*)enc)[q0 - 64 + 63 - lane];
                        u32 eN = ((volatile u32*)enc)[q0 + 64 + lane];
                        S_P = scanmax32(ePr);
                        P_n = scanmax32(eN);
                        first = false;
                    }
                    u32 P_c = scanmax32(eC);
                    u32 S_C = scanmax32(eCr);
                    // Gil-Werman window-max [p-32,p+32]
                    u32 sendS = (lane < 32) ? S_P : S_C;
                    u32 sendP = (lane < 32) ? P_n : P_c;
                    int idxP = lane ^ 32;
                    u32 a1 = (u32)__shfl((int)sendS, 63 - idxP);
                    u32 a2 = (u32)__shfl((int)sendP, idxP);
                    u32 wm = a1 > a2 ? a1 : a2;
                    bool cand = act && (wm == eC);  // no strictly-larger in window
                    u64 Mc = __ballot((int)cand);
                    u64 M = 0;
                    while (Mc) {                    // exact tie-break (rare >1 iter)
                        int c = __ffsll((long long)Mc) - 1;
                        Mc &= Mc - 1;
                        u32 vc = (u32)__shfl((int)eC, c);
                        u64 eqC = __ballot((int)(eC == vc));   // own chunk
                        u64 eqP = __ballot((int)(ePr == vc));  // prev, bit l<->prev[63-l]
                        int lo = c - 32; if (lo < 0) lo = 0;
                        u64 belowC = (c == 0) ? 0ULL
                                   : (((1ULL << c) - 1ULL) & ~((1ULL << lo) - 1ULL));
                        u64 blockP = (c <= 31) ? (eqP & ((1ULL << (32 - c)) - 1ULL))
                                               : 0ULL;
                        if (((eqC & belowC) | blockP) == 0ULL) M |= (1ULL << c);
                    }
                    if (M == 0ULL) break;
                    bool winlane = (M >> lane) & 1ULL;
                    if (winlane) { enc[p] = SENT32; alive &= ~(1u << kl); }
                    // ballot-mask suppression: 3 predicated writes per lane
                    int lo = lane - 32; if (lo < 0) lo = 0;
                    int hi = lane + 32; if (hi > 63) hi = 63;
                    u64 mwin = ((hi == 63) ? ~0ULL : ((1ULL << (hi + 1)) - 1ULL))
                             & ~((1ULL << lo) - 1ULL);
                    bool supS = !winlane && ((M & mwin & ~(1ULL << lane)) != 0ULL);
                    bool supP = (lane >= 32) &&
                                ((M & ((1ULL << (lane - 31)) - 1ULL)) != 0ULL);
                    bool supN = (lane < 32) &&
                                ((M & (~0ULL << (lane + 32))) != 0ULL);
                    if (supS) { enc[p] = 0u; alive &= ~(1u << kl); }
                    if (supP) { enc[p - 64] = 0u; if (kl > 0) alive &= ~(1u << (kl - 1)); }
                    if (supN) { enc[p + 64] = 0u; if (kl < CPW - 1) alive &= ~(1u << (kl + 1)); }
                }
            }
            __threadfence_block();
            dir ^= 1;
        }
    } else if (wave == 0) {
        // ---- generic-d exact fallback: single wave, u64 keys ----
        u64* enc64 = s_enc64_raw + DPAD;
        for (int k = 0; k < NCH; ++k) {
            int p = (k << 6) + lane;
            u32 e = enc[p];
            enc64[p] = e ? ((((u64)e) << 12) | (u64)(4095 - p)) : 0ULL;
        }
        s_enc64_raw[lane] = 0;
        s_enc64_raw[L + DPAD + lane] = 0;
        u64 alive64 = ~0ULL;
        int dir = 0;
        for (int pass = 0; pass < 2048; ++pass) {
            if (!__ballot((int)(alive64 != 0ULL))) break;
            for (int kk = 0; kk < NCH; ++kk) {
                int k = dir ? (NCH - 1 - kk) : kk;
                bool act = (alive64 >> k) & 1ULL;
                if (!__ballot((int)act)) continue;
                int p = (k << 6) + lane;
                u64 me = 0;
                if (act) {
                    me = enc64[p];
                    if (me == 0ULL) { alive64 &= ~(1ULL << k); act = false; }
                }
                if (!__ballot((int)act)) continue;
                u64 best = 0;
                int lo = p - d; if (lo < 0) lo = 0;
                int hi = p + d; if (hi > L - 1) hi = L - 1;
                if (act)
                    for (int j = lo; j <= hi; ++j)
                        if (j != p) best = best > enc64[j] ? best : enc64[j];
                if (act && best < me) {
                    enc64[p] = ~0ULL;
                    enc[p] = SENT32;
                    alive64 &= ~(1ULL << k);
                    for (int j = lo; j <= hi; ++j)
                        if (j != p) enc64[j] = 0ULL;
                }
            }
            dir ^= 1;
        }
    }
    __syncthreads();

    // ---- emit: kept -> x, else 0 ----
    float* __restrict__ orow = out + (size_t)row * L;
    #pragma unroll
    for (int t = 0; t < 2; ++t) {
        int f = t * BLOCK + tid;
        int base = 4 * f;
        uint4 ev = ((const uint4*)&enc[base])[0];
        float4 xv = ((const float4*)s_x)[f];
        float4 o;
        o.x = (ev.x == SENT32) ? xv.x : 0.0f;
        o.y = (ev.y == SENT32) ? xv.y : 0.0f;
        o.z = (ev.z == SENT32) ? xv.z : 0.0f;
        o.w = (ev.w == SENT32) ? xv.w : 0.0f;
        ((float4*)orow)[f] = o;
    }
}

extern "C" void kernel_launch(void* const* d_in, const int* in_sizes, int n_in,
                              void* d_out, int out_size, void* d_ws, size_t ws_size,
                              hipStream_t stream) {
    const float* x = (const float*)d_in[0];
    const int* dptr = (const int*)d_in[1];
    float* out = (float*)d_out;
    const int B = out_size / L;  // 128 rows, 8 waves each
    extrema1d_kernel<<<B, BLOCK, 0, stream>>>(x, dptr, out);
}

// Round 7
// 67.846 us; speedup vs baseline: 1.8741x; 1.0039x over previous
//
#include <hip/hip_runtime.h>

#define L 4096
#define BLOCK 512
#define LANES 64
#define NWAVE (BLOCK / LANES)     // 8 waves per row
#define NCH (L / LANES)           // 64 chunks of 64
#define CPW (NCH / NWAVE)         // 8 chunks per wave (contiguous segment)
#define DPAD 64
typedef unsigned long long u64;
typedef unsigned u32;
#define SENT32 0xFFFFFFFFu        // kept marker; real keys <= 0x7F800002

template<int CTRL, int RM>
static __device__ __forceinline__ u32 dpp32(u32 v) {
    u32 s = (u32)__builtin_amdgcn_update_dpp(0, (int)v, CTRL, RM, 0xf, false);
    return v > s ? v : s;   // bound_ctrl=false, old=0 -> identity off-row
}
// Inclusive 64-lane prefix-max (R4/R5/R6-verified DPP sequence).
static __device__ __forceinline__ u32 scanmax32(u32 v) {
    v = dpp32<0x111, 0xf>(v);  // row_shr:1
    v = dpp32<0x112, 0xf>(v);  // row_shr:2
    v = dpp32<0x114, 0xf>(v);  // row_shr:4
    v = dpp32<0x118, 0xf>(v);  // row_shr:8
    v = dpp32<0x142, 0xa>(v);  // row_bcast:15
    v = dpp32<0x143, 0xc>(v);  // row_bcast:31
    return v;
}

// enc[i]: active -> bits(|x|)+1; 0 = none/suppressed; SENT32 = kept.
// Monotone slot history (key -> {0|SENT32}, both terminal): an alive item is
// always read at its exact key; stale reads only over-estimate dead neighbors
// -> defer-only, never a false keep. Hence 8-wave chaotic iteration commits
// exactly the sequential-greedy fixed point; ties resolved exactly via
// equality ballots (smaller index wins = JAX stable argsort). Rep iterations
// within a visit run entirely in registers (dead values masked via ballots);
// cross-wave kills missed mid-visit are caught at the next pass's fresh read.
__global__ __launch_bounds__(BLOCK)
void extrema1d_kernel(const float* __restrict__ x,
                      const int* __restrict__ dptr,
                      float* __restrict__ out) {
    __shared__ float s_x[L];
    __shared__ u32 s_enc_raw[L + 2 * DPAD];
    __shared__ u64 s_enc64_raw[L + 2 * DPAD];  // generic-d fallback only
    u32* enc = s_enc_raw + DPAD;

    const int row = blockIdx.x;
    const int tid = threadIdx.x;
    const int lane = tid & (LANES - 1);
    const int wave = tid >> 6;
    const int d = *dptr;
    const float* __restrict__ xrow = x + (size_t)row * L;

    // ---- stage row (coalesced float4, 2 per thread) ----
    #pragma unroll
    for (int t = 0; t < 2; ++t) {
        int f = t * BLOCK + tid;
        ((float4*)s_x)[f] = ((const float4*)xrow)[f];
    }
    if (tid < 2 * DPAD)
        s_enc_raw[(tid < DPAD) ? tid : (DPAD + L + (tid - DPAD))] = 0u;
    __syncthreads();

    // ---- extrema -> keys (reference pads: dxr[L-1]=F, dxl[0]=T, neg=!(x>0))
    #pragma unroll
    for (int t = 0; t < 2; ++t) {
        int f = t * BLOCK + tid;
        int base = 4 * f;
        float4 xv = ((const float4*)s_x)[f];
        float xl = (base == 0) ? 0.0f : s_x[base - 1];
        float xr = (base + 4 >= L) ? 0.0f : s_x[base + 4];
        float nb[6] = {xl, xv.x, xv.y, xv.z, xv.w, xr};
        uint4 ev; u32* evp = (u32*)&ev;
        #pragma unroll
        for (int j = 0; j < 4; ++j) {
            int p = base + j;
            float xi = nb[j + 1];
            bool dxr = (p < L - 1) && ((nb[j + 2] - xi) > 0.0f);
            bool dxl = (p == 0) || ((xi - nb[j]) <= 0.0f);
            bool neg = !(xi > 0.0f);
            bool ext = (dxr && dxl && neg) || (!dxr && !dxl && !neg);
            evp[j] = ext ? (__float_as_uint(fabsf(xi)) + 1u) : 0u;
        }
        ((uint4*)&enc[base])[0] = ev;
    }
    __syncthreads();

    if (d == 32) {
        const int seg0 = wave * CPW;
        u32 alive = (1u << CPW) - 1u;   // bit kl <-> pos (seg0+kl)*64+lane
        int dir = 0;
        for (int pass = 0; pass < 512; ++pass) {
            if (!__ballot((int)(alive != 0u))) break;
            for (int kk = 0; kk < CPW; ++kk) {
                int kl = dir ? (CPW - 1 - kk) : kk;
                if (!__ballot((int)((alive >> kl) & 1u))) continue;
                const int q0 = (seg0 + kl) << 6;
                const int p = q0 + lane;
                // ---- visit-start: 4 independent fresh reads (pipelined) ----
                u32 eC  = ((volatile u32*)enc)[p];
                u32 eCr = ((volatile u32*)enc)[q0 + 63 - lane];
                u32 ePr = ((volatile u32*)enc)[q0 - 64 + 63 - lane];
                u32 eN  = ((volatile u32*)enc)[q0 + 64 + lane];
                bool act = (alive >> kl) & 1u;
                if (act && eC == 0u) { alive &= ~(1u << kl); act = false; }
                if (!__ballot((int)act)) continue;
                u32 S_P = scanmax32(ePr);
                u32 P_n = scanmax32(eN);
                // ---- register-resident Gauss-Seidel reps ----
                for (int rep = 0; rep < 4; ++rep) {
                    u32 P_c = scanmax32(eC);
                    u32 S_C = scanmax32(eCr);
                    // Gil-Werman window-max [p-32,p+32]
                    u32 sendS = (lane < 32) ? S_P : S_C;
                    u32 sendP = (lane < 32) ? P_n : P_c;
                    int idxP = lane ^ 32;
                    u32 a1 = (u32)__shfl((int)sendS, 63 - idxP);
                    u32 a2 = (u32)__shfl((int)sendP, idxP);
                    u32 wm = a1 > a2 ? a1 : a2;
                    bool cand = act && (wm == eC);  // no strictly-larger in window
                    u64 Mc = __ballot((int)cand);
                    u64 M = 0;
                    while (Mc) {                    // exact tie-break (rare >1 iter)
                        int c = __ffsll((long long)Mc) - 1;
                        Mc &= Mc - 1;
                        u32 vc = (u32)__shfl((int)eC, c);
                        u64 eqC = __ballot((int)(eC == vc));   // own chunk
                        u64 eqP = __ballot((int)(ePr == vc));  // prev, bit l<->prev[63-l]
                        int lo = c - 32; if (lo < 0) lo = 0;
                        u64 belowC = (c == 0) ? 0ULL
                                   : (((1ULL << c) - 1ULL) & ~((1ULL << lo) - 1ULL));
                        u64 blockP = (c <= 31) ? (eqP & ((1ULL << (32 - c)) - 1ULL))
                                               : 0ULL;
                        if (((eqC & belowC) | blockP) == 0ULL) M |= (1ULL << c);
                    }
                    if (M == 0ULL) break;
                    bool winlane = (M >> lane) & 1ULL;
                    if (winlane) { enc[p] = SENT32; alive &= ~(1u << kl); act = false; }
                    // ballot-mask suppression: 3 predicated LDS writes per lane
                    int lo = lane - 32; if (lo < 0) lo = 0;
                    int hi = lane + 32; if (hi > 63) hi = 63;
                    u64 mwin = ((hi == 63) ? ~0ULL : ((1ULL << (hi + 1)) - 1ULL))
                             & ~((1ULL << lo) - 1ULL);
                    bool supS = !winlane && ((M & mwin & ~(1ULL << lane)) != 0ULL);
                    bool supP = (lane >= 32) &&
                                ((M & ((1ULL << (lane - 31)) - 1ULL)) != 0ULL);
                    bool supN = (lane < 32) &&
                                ((M & (~0ULL << (lane + 32))) != 0ULL);
                    if (supS) { enc[p] = 0u; alive &= ~(1u << kl); act = false; }
                    if (supP) { enc[p - 64] = 0u; if (kl > 0) alive &= ~(1u << (kl - 1)); }
                    if (supN) { enc[p + 64] = 0u; if (kl < CPW - 1) alive &= ~(1u << (kl + 1)); }
                    if (!__ballot((int)act)) break;
                    // ---- in-register death propagation for the next rep ----
                    u64 deadC = __ballot((int)(winlane || supS));
                    if ((deadC >> lane) & 1ULL) eC = 0u;
                    if ((deadC >> (63 - lane)) & 1ULL) eCr = 0u;
                    u64 deadP = __ballot((int)supP);
                    if (deadP) {
                        if ((deadP >> (63 - lane)) & 1ULL) ePr = 0u;
                        S_P = scanmax32(ePr);
                    }
                    u64 deadN = __ballot((int)supN);
                    if (deadN) {
                        if ((deadN >> lane) & 1ULL) eN = 0u;
                        P_n = scanmax32(eN);
                    }
                }
            }
            __threadfence_block();
            dir ^= 1;
        }
    } else if (wave == 0) {
        // ---- generic-d exact fallback: single wave, u64 keys ----
        u64* enc64 = s_enc64_raw + DPAD;
        for (int k = 0; k < NCH; ++k) {
            int p = (k << 6) + lane;
            u32 e = enc[p];
            enc64[p] = e ? ((((u64)e) << 12) | (u64)(4095 - p)) : 0ULL;
        }
        s_enc64_raw[lane] = 0;
        s_enc64_raw[L + DPAD + lane] = 0;
        u64 alive64 = ~0ULL;
        int dir = 0;
        for (int pass = 0; pass < 2048; ++pass) {
            if (!__ballot((int)(alive64 != 0ULL))) break;
            for (int kk = 0; kk < NCH; ++kk) {
                int k = dir ? (NCH - 1 - kk) : kk;
                bool act = (alive64 >> k) & 1ULL;
                if (!__ballot((int)act)) continue;
                int p = (k << 6) + lane;
                u64 me = 0;
                if (act) {
                    me = enc64[p];
                    if (me == 0ULL) { alive64 &= ~(1ULL << k); act = false; }
                }
                if (!__ballot((int)act)) continue;
                u64 best = 0;
                int lo = p - d; if (lo < 0) lo = 0;
                int hi = p + d; if (hi > L - 1) hi = L - 1;
                if (act)
                    for (int j = lo; j <= hi; ++j)
                        if (j != p) best = best > enc64[j] ? best : enc64[j];
                if (act && best < me) {
                    enc64[p] = ~0ULL;
                    enc[p] = SENT32;
                    alive64 &= ~(1ULL << k);
                    for (int j = lo; j <= hi; ++j)
                        if (j != p) enc64[j] = 0ULL;
                }
            }
            dir ^= 1;
        }
    }
    __syncthreads();

    // ---- emit: kept -> x, else 0 ----
    float* __restrict__ orow = out + (size_t)row * L;
    #pragma unroll
    for (int t = 0; t < 2; ++t) {
        int f = t * BLOCK + tid;
        int base = 4 * f;
        uint4 ev = ((const uint4*)&enc[base])[0];
        float4 xv = ((const float4*)s_x)[f];
        float4 o;
        o.x = (ev.x == SENT32) ? xv.x : 0.0f;
        o.y = (ev.y == SENT32) ? xv.y : 0.0f;
        o.z = (ev.z == SENT32) ? xv.z : 0.0f;
        o.w = (ev.w == SENT32) ? xv.w : 0.0f;
        ((float4*)orow)[f] = o;
    }
}

extern "C" void kernel_launch(void* const* d_in, const int* in_sizes, int n_in,
                              void* d_out, int out_size, void* d_ws, size_t ws_size,
                              hipStream_t stream) {
    const float* x = (const float*)d_in[0];
    const int* dptr = (const int*)d_in[1];
    float* out = (float*)d_out;
    const int B = out_size / L;  // 128 rows, 8 waves each
    extrema1d_kernel<<<B, BLOCK, 0, stream>>>(x, dptr, out);
}

// Round 8
// 63.517 us; speedup vs baseline: 2.0018x; 1.0681x over previous
//
#include <hip/hip_runtime.h>

#define L 4096
#define BLOCK 1024
#define LANES 64
#define NWAVE (BLOCK / LANES)     // 16 waves per row
#define NCH (L / LANES)           // 64 chunks of 64
#define CPW (NCH / NWAVE)         // 4 chunks per wave (contiguous segment)
#define DPAD 64
typedef unsigned long long u64;
typedef unsigned u32;
#define SENT32 0xFFFFFFFFu        // kept marker; real keys <= 0x7F800002

template<int CTRL, int RM>
static __device__ __forceinline__ u32 dpp32(u32 v) {
    u32 s = (u32)__builtin_amdgcn_update_dpp(0, (int)v, CTRL, RM, 0xf, false);
    return v > s ? v : s;   // bound_ctrl=false, old=0 -> identity off-row
}
// Inclusive 64-lane prefix-max (R4..R7-verified DPP sequence).
static __device__ __forceinline__ u32 scanmax32(u32 v) {
    v = dpp32<0x111, 0xf>(v);  // row_shr:1
    v = dpp32<0x112, 0xf>(v);  // row_shr:2
    v = dpp32<0x114, 0xf>(v);  // row_shr:4
    v = dpp32<0x118, 0xf>(v);  // row_shr:8
    v = dpp32<0x142, 0xa>(v);  // row_bcast:15
    v = dpp32<0x143, 0xc>(v);  // row_bcast:31
    return v;
}

// enc[i]: active -> bits(|x|)+1; 0 = none/suppressed; SENT32 = kept.
// Monotone slot history (key -> {0|SENT32}, both terminal): an alive item is
// always read at its exact key; stale reads only over-estimate dead neighbors
// -> defer-only, never a false keep => chaotic multi-wave iteration commits
// exactly the sequential-greedy fixed point. Ties resolved exactly via
// equality ballots (smaller index wins = JAX stable argsort). 16 waves x 4
// chunks: per-pass serial path is 4 chunk-visits; segment-boundary kills are
// healed by the visit-start eC==0 check on the following pass.
__global__ __launch_bounds__(BLOCK)
void extrema1d_kernel(const float* __restrict__ x,
                      const int* __restrict__ dptr,
                      float* __restrict__ out) {
    __shared__ float s_x[L];
    __shared__ u32 s_enc_raw[L + 2 * DPAD];
    __shared__ u64 s_enc64_raw[L + 2 * DPAD];  // generic-d fallback only
    u32* enc = s_enc_raw + DPAD;

    const int row = blockIdx.x;
    const int tid = threadIdx.x;
    const int lane = tid & (LANES - 1);
    const int wave = tid >> 6;
    const int d = *dptr;
    const float* __restrict__ xrow = x + (size_t)row * L;

    // ---- stage row (coalesced float4, 1 per thread) ----
    ((float4*)s_x)[tid] = ((const float4*)xrow)[tid];
    if (tid < 2 * DPAD)
        s_enc_raw[(tid < DPAD) ? tid : (DPAD + L + (tid - DPAD))] = 0u;
    __syncthreads();

    // ---- extrema -> keys (reference pads: dxr[L-1]=F, dxl[0]=T, neg=!(x>0))
    {
        int base = 4 * tid;
        float4 xv = ((const float4*)s_x)[tid];
        float xl = (base == 0) ? 0.0f : s_x[base - 1];
        float xr = (base + 4 >= L) ? 0.0f : s_x[base + 4];
        float nb[6] = {xl, xv.x, xv.y, xv.z, xv.w, xr};
        uint4 ev; u32* evp = (u32*)&ev;
        #pragma unroll
        for (int j = 0; j < 4; ++j) {
            int p = base + j;
            float xi = nb[j + 1];
            bool dxr = (p < L - 1) && ((nb[j + 2] - xi) > 0.0f);
            bool dxl = (p == 0) || ((xi - nb[j]) <= 0.0f);
            bool neg = !(xi > 0.0f);
            bool ext = (dxr && dxl && neg) || (!dxr && !dxl && !neg);
            evp[j] = ext ? (__float_as_uint(fabsf(xi)) + 1u) : 0u;
        }
        ((uint4*)&enc[base])[0] = ev;
    }
    __syncthreads();

    if (d == 32) {
        const int seg0 = wave * CPW;
        u32 alive = (1u << CPW) - 1u;   // bit kl <-> pos (seg0+kl)*64+lane
        int dir = 0;
        for (int pass = 0; pass < 512; ++pass) {
            if (!__ballot((int)(alive != 0u))) break;
            for (int kk = 0; kk < CPW; ++kk) {
                int kl = dir ? (CPW - 1 - kk) : kk;
                if (!__ballot((int)((alive >> kl) & 1u))) continue;
                const int q0 = (seg0 + kl) << 6;
                const int p = q0 + lane;
                // ---- visit-start: 4 independent fresh reads (pipelined) ----
                u32 eC  = ((volatile u32*)enc)[p];
                u32 eCr = ((volatile u32*)enc)[q0 + 63 - lane];
                u32 ePr = ((volatile u32*)enc)[q0 - 64 + 63 - lane];
                u32 eN  = ((volatile u32*)enc)[q0 + 64 + lane];
                bool act = (alive >> kl) & 1u;
                if (act && eC == 0u) { alive &= ~(1u << kl); act = false; }
                if (!__ballot((int)act)) continue;
                u32 S_P = scanmax32(ePr);
                u32 P_n = scanmax32(eN);
                // ---- register-resident Gauss-Seidel reps ----
                for (int rep = 0; rep < 3; ++rep) {
                    u32 P_c = scanmax32(eC);
                    u32 S_C = scanmax32(eCr);
                    // Gil-Werman window-max [p-32,p+32]
                    u32 sendS = (lane < 32) ? S_P : S_C;
                    u32 sendP = (lane < 32) ? P_n : P_c;
                    int idxP = lane ^ 32;
                    u32 a1 = (u32)__shfl((int)sendS, 63 - idxP);
                    u32 a2 = (u32)__shfl((int)sendP, idxP);
                    u32 wm = a1 > a2 ? a1 : a2;
                    bool cand = act && (wm == eC);  // no strictly-larger in window
                    u64 Mc = __ballot((int)cand);
                    u64 M = 0;
                    while (Mc) {                    // exact tie-break (rare >1 iter)
                        int c = __ffsll((long long)Mc) - 1;
                        Mc &= Mc - 1;
                        u32 vc = (u32)__shfl((int)eC, c);
                        u64 eqC = __ballot((int)(eC == vc));   // own chunk
                        u64 eqP = __ballot((int)(ePr == vc));  // prev, bit l<->prev[63-l]
                        int lo = c - 32; if (lo < 0) lo = 0;
                        u64 belowC = (c == 0) ? 0ULL
                                   : (((1ULL << c) - 1ULL) & ~((1ULL << lo) - 1ULL));
                        u64 blockP = (c <= 31) ? (eqP & ((1ULL << (32 - c)) - 1ULL))
                                               : 0ULL;
                        if (((eqC & belowC) | blockP) == 0ULL) M |= (1ULL << c);
                    }
                    if (M == 0ULL) break;
                    bool winlane = (M >> lane) & 1ULL;
                    if (winlane) { enc[p] = SENT32; alive &= ~(1u << kl); act = false; }
                    // ballot-mask suppression: 3 predicated LDS writes per lane
                    int lo = lane - 32; if (lo < 0) lo = 0;
                    int hi = lane + 32; if (hi > 63) hi = 63;
                    u64 mwin = ((hi == 63) ? ~0ULL : ((1ULL << (hi + 1)) - 1ULL))
                             & ~((1ULL << lo) - 1ULL);
                    bool supS = !winlane && ((M & mwin & ~(1ULL << lane)) != 0ULL);
                    bool supP = (lane >= 32) &&
                                ((M & ((1ULL << (lane - 31)) - 1ULL)) != 0ULL);
                    bool supN = (lane < 32) &&
                                ((M & (~0ULL << (lane + 32))) != 0ULL);
                    if (supS) { enc[p] = 0u; alive &= ~(1u << kl); act = false; }
                    if (supP) { enc[p - 64] = 0u; if (kl > 0) alive &= ~(1u << (kl - 1)); }
                    if (supN) { enc[p + 64] = 0u; if (kl < CPW - 1) alive &= ~(1u << (kl + 1)); }
                    if (!__ballot((int)act)) break;
                    // ---- in-register death propagation for the next rep ----
                    u64 deadC = __ballot((int)(winlane || supS));
                    if ((deadC >> lane) & 1ULL) eC = 0u;
                    if ((deadC >> (63 - lane)) & 1ULL) eCr = 0u;
                    u64 deadP = __ballot((int)supP);
                    if (deadP) {
                        if ((deadP >> (63 - lane)) & 1ULL) ePr = 0u;
                        S_P = scanmax32(ePr);
                    }
                    u64 deadN = __ballot((int)supN);
                    if (deadN) {
                        if ((deadN >> lane) & 1ULL) eN = 0u;
                        P_n = scanmax32(eN);
                    }
                }
            }
            __threadfence_block();
            dir ^= 1;
        }
    } else if (wave == 0) {
        // ---- generic-d exact fallback: single wave, u64 keys ----
        u64* enc64 = s_enc64_raw + DPAD;
        for (int k = 0; k < NCH; ++k) {
            int p = (k << 6) + lane;
            u32 e = enc[p];
            enc64[p] = e ? ((((u64)e) << 12) | (u64)(4095 - p)) : 0ULL;
        }
        s_enc64_raw[lane] = 0;
        s_enc64_raw[L + DPAD + lane] = 0;
        u64 alive64 = ~0ULL;
        int dir = 0;
        for (int pass = 0; pass < 2048; ++pass) {
            if (!__ballot((int)(alive64 != 0ULL))) break;
            for (int kk = 0; kk < NCH; ++kk) {
                int k = dir ? (NCH - 1 - kk) : kk;
                bool act = (alive64 >> k) & 1ULL;
                if (!__ballot((int)act)) continue;
                int p = (k << 6) + lane;
                u64 me = 0;
                if (act) {
                    me = enc64[p];
                    if (me == 0ULL) { alive64 &= ~(1ULL << k); act = false; }
                }
                if (!__ballot((int)act)) continue;
                u64 best = 0;
                int lo = p - d; if (lo < 0) lo = 0;
                int hi = p + d; if (hi > L - 1) hi = L - 1;
                if (act)
                    for (int j = lo; j <= hi; ++j)
                        if (j != p) best = best > enc64[j] ? best : enc64[j];
                if (act && best < me) {
                    enc64[p] = ~0ULL;
                    enc[p] = SENT32;
                    alive64 &= ~(1ULL << k);
                    for (int j = lo; j <= hi; ++j)
                        if (j != p) enc64[j] = 0ULL;
                }
            }
            dir ^= 1;
        }
    }
    __syncthreads();

    // ---- emit: kept -> x, else 0 ----
    float* __restrict__ orow = out + (size_t)row * L;
    {
        uint4 ev = ((const uint4*)&enc[4 * tid])[0];
        float4 xv = ((const float4*)s_x)[tid];
        float4 o;
        o.x = (ev.x == SENT32) ? xv.x : 0.0f;
        o.y = (ev.y == SENT32) ? xv.y : 0.0f;
        o.z = (ev.z == SENT32) ? xv.z : 0.0f;
        o.w = (ev.w == SENT32) ? xv.w : 0.0f;
        ((float4*)orow)[tid] = o;
    }
}

extern "C" void kernel_launch(void* const* d_in, const int* in_sizes, int n_in,
                              void* d_out, int out_size, void* d_ws, size_t ws_size,
                              hipStream_t stream) {
    const float* x = (const float*)d_in[0];
    const int* dptr = (const int*)d_in[1];
    float* out = (float*)d_out;
    const int B = out_size / L;  // 128 rows, 16 waves each
    extrema1d_kernel<<<B, BLOCK, 0, stream>>>(x, dptr, out);
}

// Round 9
// 62.763 us; speedup vs baseline: 2.0259x; 1.0120x over previous
//
#include <hip/hip_runtime.h>

#define L 4096
#define BLOCK 1024
#define LANES 64
#define NWAVE (BLOCK / LANES)     // 16 waves per row
#define NCH (L / LANES)           // 64 chunks of 64
#define CPW (NCH / NWAVE)         // 4 chunks per wave (contiguous segment)
#define DPAD 64
typedef unsigned long long u64;
typedef unsigned u32;
#define SENT32 0xFFFFFFFFu        // kept marker; real keys <= 0x7F800002

template<int CTRL, int RM>
static __device__ __forceinline__ u32 dpp32(u32 v) {
    u32 s = (u32)__builtin_amdgcn_update_dpp(0, (int)v, CTRL, RM, 0xf, false);
    return v > s ? v : s;   // bound_ctrl=false, old=0 -> identity off-row
}
// Inclusive 64-lane prefix-max (R4..R8-verified DPP sequence).
static __device__ __forceinline__ u32 scanmax32(u32 v) {
    v = dpp32<0x111, 0xf>(v);  // row_shr:1
    v = dpp32<0x112, 0xf>(v);  // row_shr:2
    v = dpp32<0x114, 0xf>(v);  // row_shr:4
    v = dpp32<0x118, 0xf>(v);  // row_shr:8
    v = dpp32<0x142, 0xa>(v);  // row_bcast:15
    v = dpp32<0x143, 0xc>(v);  // row_bcast:31
    return v;
}
static __device__ __forceinline__ u32 rev64(u32 v, int lane) {
    return (u32)__shfl((int)v, 63 - lane);
}

// enc[i]: active -> bits(|x|)+1; 0 = none/suppressed; SENT32 = kept.
// Register-carry soundness: cross-wave writes reach only chunk0's lower 32 /
// chunk3's upper 32 slots (winners live in their own segment, radius 32).
// Those slots are outside every window of inner-chunk items, so inner chunks'
// decision inputs carried in registers are EXACT; boundary chunks (0,3) are
// re-read fresh from LDS each visit. Out-of-window staleness only
// over-estimates dead neighbors -> defer-only, never a false keep; ties
// resolved exactly via equality ballots (smaller index first = JAX argsort).
template<int KL>
static __device__ __forceinline__ void visit(u32* enc, int seg0, int lane,
                                             u32& alive,
                                             u32& r0, u32& r1, u32& r2, u32& r3) {
    if (!__ballot((int)((alive >> KL) & 1u))) return;
    const int q0 = (seg0 + KL) << 6;
    const int p = q0 + lane;
    u32& own   = (KL == 0) ? r0 : (KL == 1) ? r1 : (KL == 2) ? r2 : r3;
    u32 dumP = 0, dumN = 0;
    u32& prevR = (KL == 0) ? dumP : (KL == 1) ? r0 : (KL == 2) ? r1 : r2;
    u32& nextR = (KL == 3) ? dumN : (KL == 0) ? r1 : (KL == 1) ? r2 : r3;

    u32 eC;
    if constexpr (KL == 0 || KL == 3) eC = ((volatile u32*)enc)[p];
    else eC = own;
    bool act = (alive >> KL) & 1u;
    if (act && eC == 0u) { alive &= ~(1u << KL); act = false; }
    if (!__ballot((int)act)) { own = eC; return; }

    u32 eP, eN;
    if constexpr (KL == 0) eP = ((volatile u32*)enc)[q0 - 64 + lane];
    else eP = prevR;
    if constexpr (KL == 3) eN = ((volatile u32*)enc)[q0 + 64 + lane];
    else eN = nextR;

    u32 ePr = rev64(eP, lane);
    u32 S_P = scanmax32(ePr);
    u32 P_n = scanmax32(eN);

    for (int rep = 0; rep < 3; ++rep) {
        u32 P_c = scanmax32(eC);
        u32 S_C = scanmax32(rev64(eC, lane));
        // Gil-Werman window-max [p-32,p+32]
        u32 sendS = (lane < 32) ? S_P : S_C;
        u32 sendP = (lane < 32) ? P_n : P_c;
        int idxP = lane ^ 32;
        u32 a1 = (u32)__shfl((int)sendS, 63 - idxP);
        u32 a2 = (u32)__shfl((int)sendP, idxP);
        u32 wm = a1 > a2 ? a1 : a2;
        bool cand = act && (wm == eC);      // no strictly-larger in window
        u64 Mc = __ballot((int)cand);
        u64 M = 0;
        while (Mc) {                        // exact tie-break (rare >1 iter)
            int c = __ffsll((long long)Mc) - 1;
            Mc &= Mc - 1;
            u32 vc = (u32)__shfl((int)eC, c);
            u64 eqC = __ballot((int)(eC == vc));   // own chunk, natural order
            u64 eqP = __ballot((int)(ePr == vc));  // prev, bit l<->prev[63-l]
            int lo = c - 32; if (lo < 0) lo = 0;
            u64 belowC = (c == 0) ? 0ULL
                       : (((1ULL << c) - 1ULL) & ~((1ULL << lo) - 1ULL));
            u64 blockP = (c <= 31) ? (eqP & ((1ULL << (32 - c)) - 1ULL)) : 0ULL;
            if (((eqC & belowC) | blockP) == 0ULL) M |= (1ULL << c);
        }
        if (M == 0ULL) break;
        bool winlane = (M >> lane) & 1ULL;
        if (winlane) { enc[p] = SENT32; eC = SENT32; alive &= ~(1u << KL); act = false; }
        // ballot-mask suppression: up to 3 predicated LDS writes per lane
        int lo = lane - 32; if (lo < 0) lo = 0;
        int hi = lane + 32; if (hi > 63) hi = 63;
        u64 mwin = ((hi == 63) ? ~0ULL : ((1ULL << (hi + 1)) - 1ULL))
                 & ~((1ULL << lo) - 1ULL);
        bool supS = !winlane && ((M & mwin & ~(1ULL << lane)) != 0ULL);
        bool supP = (lane >= 32) && ((M & ((1ULL << (lane - 31)) - 1ULL)) != 0ULL);
        bool supN = (lane < 32) && ((M & (~0ULL << (lane + 32))) != 0ULL);
        if (supS) { enc[p] = 0u; eC = 0u; alive &= ~(1u << KL); act = false; }
        if (supP) { enc[p - 64] = 0u; eP = 0u; if (KL > 0) alive &= ~(1u << (KL - 1)); }
        if (supN) { enc[p + 64] = 0u; eN = 0u; if (KL < 3) alive &= ~(1u << (KL + 1)); }
        if (!__ballot((int)act)) break;
        if (__ballot((int)supP)) { ePr = rev64(eP, lane); S_P = scanmax32(ePr); }
        if (__ballot((int)supN)) { P_n = scanmax32(eN); }
    }
    // write back register-carried state
    own = eC;
    if constexpr (KL > 0) prevR = eP;
    if constexpr (KL < 3) nextR = eN;
}

__global__ __launch_bounds__(BLOCK)
void extrema1d_kernel(const float* __restrict__ x,
                      const int* __restrict__ dptr,
                      float* __restrict__ out) {
    __shared__ float s_x[L];
    __shared__ u32 s_enc_raw[L + 2 * DPAD];
    __shared__ u64 s_enc64_raw[L + 2 * DPAD];  // generic-d fallback only
    u32* enc = s_enc_raw + DPAD;

    const int row = blockIdx.x;
    const int tid = threadIdx.x;
    const int lane = tid & (LANES - 1);
    const int wave = tid >> 6;
    const int d = *dptr;
    const float* __restrict__ xrow = x + (size_t)row * L;

    // ---- stage row (coalesced float4, 1 per thread) ----
    ((float4*)s_x)[tid] = ((const float4*)xrow)[tid];
    if (tid < 2 * DPAD)
        s_enc_raw[(tid < DPAD) ? tid : (DPAD + L + (tid - DPAD))] = 0u;
    __syncthreads();

    // ---- extrema -> keys (reference pads: dxr[L-1]=F, dxl[0]=T, neg=!(x>0))
    {
        int base = 4 * tid;
        float4 xv = ((const float4*)s_x)[tid];
        float xl = (base == 0) ? 0.0f : s_x[base - 1];
        float xr = (base + 4 >= L) ? 0.0f : s_x[base + 4];
        float nb[6] = {xl, xv.x, xv.y, xv.z, xv.w, xr};
        uint4 ev; u32* evp = (u32*)&ev;
        #pragma unroll
        for (int j = 0; j < 4; ++j) {
            int p = base + j;
            float xi = nb[j + 1];
            bool dxr = (p < L - 1) && ((nb[j + 2] - xi) > 0.0f);
            bool dxl = (p == 0) || ((xi - nb[j]) <= 0.0f);
            bool neg = !(xi > 0.0f);
            bool ext = (dxr && dxl && neg) || (!dxr && !dxl && !neg);
            evp[j] = ext ? (__float_as_uint(fabsf(xi)) + 1u) : 0u;
        }
        ((uint4*)&enc[base])[0] = ev;
    }
    __syncthreads();

    if (d == 32) {
        const int seg0 = wave * CPW;
        u32 alive = (1u << CPW) - 1u;   // bit kl <-> pos (seg0+kl)*64+lane
        // register-carried chunk states
        u32 r0 = enc[((seg0 + 0) << 6) + lane];
        u32 r1 = enc[((seg0 + 1) << 6) + lane];
        u32 r2 = enc[((seg0 + 2) << 6) + lane];
        u32 r3 = enc[((seg0 + 3) << 6) + lane];
        int dir = 0;
        for (int pass = 0; pass < 512; ++pass) {
            if (!__ballot((int)(alive != 0u))) break;
            if (dir == 0) {
                visit<0>(enc, seg0, lane, alive, r0, r1, r2, r3);
                visit<1>(enc, seg0, lane, alive, r0, r1, r2, r3);
                visit<2>(enc, seg0, lane, alive, r0, r1, r2, r3);
                visit<3>(enc, seg0, lane, alive, r0, r1, r2, r3);
            } else {
                visit<3>(enc, seg0, lane, alive, r0, r1, r2, r3);
                visit<2>(enc, seg0, lane, alive, r0, r1, r2, r3);
                visit<1>(enc, seg0, lane, alive, r0, r1, r2, r3);
                visit<0>(enc, seg0, lane, alive, r0, r1, r2, r3);
            }
            __threadfence_block();
            dir ^= 1;
        }
    } else if (wave == 0) {
        // ---- generic-d exact fallback: single wave, u64 keys ----
        u64* enc64 = s_enc64_raw + DPAD;
        for (int k = 0; k < NCH; ++k) {
            int p = (k << 6) + lane;
            u32 e = enc[p];
            enc64[p] = e ? ((((u64)e) << 12) | (u64)(4095 - p)) : 0ULL;
        }
        s_enc64_raw[lane] = 0;
        s_enc64_raw[L + DPAD + lane] = 0;
        u64 alive64 = ~0ULL;
        int dir = 0;
        for (int pass = 0; pass < 2048; ++pass) {
            if (!__ballot((int)(alive64 != 0ULL))) break;
            for (int kk = 0; kk < NCH; ++kk) {
                int k = dir ? (NCH - 1 - kk) : kk;
                bool act = (alive64 >> k) & 1ULL;
                if (!__ballot((int)act)) continue;
                int p = (k << 6) + lane;
                u64 me = 0;
                if (act) {
                    me = enc64[p];
                    if (me == 0ULL) { alive64 &= ~(1ULL << k); act = false; }
                }
                if (!__ballot((int)act)) continue;
                u64 best = 0;
                int lo = p - d; if (lo < 0) lo = 0;
                int hi = p + d; if (hi > L - 1) hi = L - 1;
                if (act)
                    for (int j = lo; j <= hi; ++j)
                        if (j != p) best = best > enc64[j] ? best : enc64[j];
                if (act && best < me) {
                    enc64[p] = ~0ULL;
                    enc[p] = SENT32;
                    alive64 &= ~(1ULL << k);
                    for (int j = lo; j <= hi; ++j)
                        if (j != p) enc64[j] = 0ULL;
                }
            }
            dir ^= 1;
        }
    }
    __syncthreads();

    // ---- emit: kept -> x, else 0 ----
    float* __restrict__ orow = out + (size_t)row * L;
    {
        uint4 ev = ((const uint4*)&enc[4 * tid])[0];
        float4 xv = ((const float4*)s_x)[tid];
        float4 o;
        o.x = (ev.x == SENT32) ? xv.x : 0.0f;
        o.y = (ev.y == SENT32) ? xv.y : 0.0f;
        o.z = (ev.z == SENT32) ? xv.z : 0.0f;
        o.w = (ev.w == SENT32) ? xv.w : 0.0f;
        ((float4*)orow)[tid] = o;
    }
}

extern "C" void kernel_launch(void* const* d_in, const int* in_sizes, int n_in,
                              void* d_out, int out_size, void* d_ws, size_t ws_size,
                              hipStream_t stream) {
    const float* x = (const float*)d_in[0];
    const int* dptr = (const int*)d_in[1];
    float* out = (float*)d_out;
    const int B = out_size / L;  // 128 rows, 16 waves each
    extrema1d_kernel<<<B, BLOCK, 0, stream>>>(x, dptr, out);
}